// Round 6
// baseline (109.120 us; speedup 1.0000x reference)
//
#include <hip/hip_runtime.h>
#include <hip/hip_bf16.h>
#include <math.h>

#define H 2048
#define V 50257
#define NB_LOG 1571          // ceil(V/32) logits blocks, 32 rows each
#define NB_GRU 384           // 12288 GRU rows / 32
#define NPART NB_LOG

typedef float f4 __attribute__((ext_vector_type(4)));

__device__ __forceinline__ f4 ntload(const f4* p) {
    return __builtin_nontemporal_load(p);
}

__device__ __forceinline__ float wave_reduce_sum(float x) {
    #pragma unroll
    for (int off = 32; off; off >>= 1) x += __shfl_down(x, off, 64);
    return x;
}

// ---------------------------------------------------------------------------
// K_A: mega matvec, one launch for ALL heavy HBM traffic (512 MB).
// 256-thread blocks (4 waves), 8 rows per wave => 32 rows per block.
// Multiplying vector PRELOADED into 8 f4 regs/lane (lane l only needs
// vec[l + i*64]); hot loop is pure weight streaming: 8 parallel row streams,
// unroll 2 => 16 loads in flight.
// Blocks [0, NB_LOG): logits rows + block-local softmax partial (m, sumexp).
// Blocks [NB_LOG, ..): GRU rows -> gi / gh.
// ---------------------------------------------------------------------------
__global__ __launch_bounds__(256, 3) void mega_matvec_kernel(
    const float* __restrict__ word, const float* __restrict__ h0,
    const float* __restrict__ w_ih, const float* __restrict__ w_hh,
    const float* __restrict__ b_ih, const float* __restrict__ b_hh,
    const float* __restrict__ lin_w, const float* __restrict__ lin_b,
    float* __restrict__ gi, float* __restrict__ gh,
    float* __restrict__ logits, float* __restrict__ pm,
    float* __restrict__ ps) {
    const int lane = threadIdx.x & 63;
    const int wid = threadIdx.x >> 6;          // 0..3
    __shared__ float lbuf[32];

    const float* Wm;
    const f4* vec;
    const float* bias;
    float* dst;
    int r0, maxrow;
    const bool is_log = ((int)blockIdx.x < NB_LOG);
    if (is_log) {
        Wm = lin_w; vec = reinterpret_cast<const f4*>(h0);
        bias = lin_b; dst = logits;
        r0 = blockIdx.x * 32 + wid * 8;
        maxrow = V;
    } else {
        const int g = blockIdx.x - NB_LOG;     // 0..383
        if (g < 192) {
            Wm = w_ih; vec = reinterpret_cast<const f4*>(word);
            bias = b_ih; dst = gi;
            r0 = g * 32 + wid * 8;
        } else {
            Wm = w_hh; vec = reinterpret_cast<const f4*>(h0);
            bias = b_hh; dst = gh;
            r0 = (g - 192) * 32 + wid * 8;
        }
        maxrow = 3 * H;
    }

    // preload the multiplying vector: lane l uses exactly vec[l + i*64]
    f4 x[8];
    #pragma unroll
    for (int i = 0; i < 8; ++i) x[i] = vec[lane + i * 64];

    int q[8];
    const f4* wrow[8];
    #pragma unroll
    for (int r = 0; r < 8; ++r) {
        q[r] = min(r0 + r, maxrow - 1);
        wrow[r] = reinterpret_cast<const f4*>(Wm + (size_t)q[r] * H);
    }

    float acc[8];
    #pragma unroll
    for (int r = 0; r < 8; ++r) acc[r] = 0.f;

    #pragma unroll 2
    for (int i = 0; i < 8; ++i) {
        const int k = lane + i * 64;
        #pragma unroll
        for (int r = 0; r < 8; ++r) {
            f4 p = ntload(&wrow[r][k]);
            acc[r] += p.x * x[i].x + p.y * x[i].y + p.z * x[i].z + p.w * x[i].w;
        }
    }
    #pragma unroll
    for (int r = 0; r < 8; ++r) acc[r] = wave_reduce_sum(acc[r]);

    if (lane == 0) {
        #pragma unroll
        for (int r = 0; r < 8; ++r) {
            const float v = acc[r] + bias[q[r]];
            if (r0 + r < maxrow) dst[r0 + r] = v;
            if (is_log) lbuf[wid * 8 + r] = (r0 + r < maxrow) ? v : -INFINITY;
        }
    }
    if (is_log) {
        __syncthreads();
        if (threadIdx.x < 32) {
            const float xv = lbuf[threadIdx.x];
            float m = xv;
            #pragma unroll
            for (int off = 16; off; off >>= 1)
                m = fmaxf(m, __shfl_xor(m, off, 32));
            float s = expf(xv - m);         // exp(-inf - m) == 0 for pad rows
            #pragma unroll
            for (int off = 16; off; off >>= 1)
                s += __shfl_xor(s, off, 32);
            if (threadIdx.x == 0) {
                pm[blockIdx.x] = m;
                ps[blockIdx.x] = s;
            }
        }
    }
}

// ---------------------------------------------------------------------------
// K_B: finish. Blocks [0,50): combine NPART partials (L2/L3-resident,
// redundant per block) then probs over 1024 logits each. Block 50: gates.
// ---------------------------------------------------------------------------
__global__ __launch_bounds__(256) void finish_kernel(
    const float* __restrict__ logits, const float* __restrict__ pm,
    const float* __restrict__ ps, const float* __restrict__ gi,
    const float* __restrict__ gh, const float* __restrict__ h0,
    float* __restrict__ out) {
    if ((int)blockIdx.x < 50) {
        __shared__ float redM[4], redS[4];
        __shared__ float sM, sInvS;
        const int lane = threadIdx.x & 63;
        const int wid = threadIdx.x >> 6;

        float M = -INFINITY, S = 0.f;
        for (int p = threadIdx.x; p < NPART; p += 256) {
            const float m = pm[p], s = ps[p];
            const float Mn = fmaxf(M, m);
            S = S * expf(M - Mn) + s * expf(m - Mn);
            M = Mn;
        }
        #pragma unroll
        for (int off = 32; off; off >>= 1) {
            const float Mo = __shfl_xor(M, off, 64);
            const float So = __shfl_xor(S, off, 64);
            const float Mn = fmaxf(M, Mo);
            S = S * expf(M - Mn) + So * expf(Mo - Mn);
            M = Mn;
        }
        if (lane == 0) { redM[wid] = M; redS[wid] = S; }
        __syncthreads();
        if (threadIdx.x == 0) {
            float M4 = redM[0], S4 = redS[0];
            #pragma unroll
            for (int w = 1; w < 4; ++w) {
                const float Mn = fmaxf(M4, redM[w]);
                S4 = S4 * expf(M4 - Mn) + redS[w] * expf(redM[w] - Mn);
                M4 = Mn;
            }
            sM = M4;
            sInvS = 1.f / S4;
        }
        __syncthreads();
        const float gm = sM, gis = sInvS;
        const int base = blockIdx.x * 1024 + threadIdx.x;
        #pragma unroll
        for (int i = 0; i < 4; ++i) {
            const int v = base + i * 256;
            if (v < V) out[v] = expf(logits[v] - gm) * gis;
        }
    } else {
        // gate math: 2048 elements, 256 threads x 8
        #pragma unroll
        for (int i = 0; i < 8; ++i) {
            const int j = threadIdx.x + i * 256;
            const float r = 1.f / (1.f + expf(-(gi[j] + gh[j])));
            const float z = 1.f / (1.f + expf(-(gi[H + j] + gh[H + j])));
            const float n = tanhf(gi[2 * H + j] + r * gh[2 * H + j]);
            out[V + j] = (1.f - z) * n + z * h0[j];
        }
    }
}

extern "C" void kernel_launch(void* const* d_in, const int* in_sizes, int n_in,
                              void* d_out, int out_size, void* d_ws, size_t ws_size,
                              hipStream_t stream) {
    const float* word = (const float*)d_in[0];
    const float* hidden = (const float*)d_in[1];   // h0, 2048 f32
    const float* w_ih = (const float*)d_in[2];
    const float* w_hh = (const float*)d_in[3];
    const float* b_ih = (const float*)d_in[4];
    const float* b_hh = (const float*)d_in[5];
    const float* lin_w = (const float*)d_in[6];
    const float* lin_b = (const float*)d_in[7];

    float* out = (float*)d_out;              // [0:V] probs, [V:V+H] h_new
    float* ws = (float*)d_ws;
    float* logits = ws;                      // V (pad to 50304)
    float* pm = ws + 50304;                  // NPART (pad to 1600)
    float* ps = ws + 50304 + 1600;           // NPART
    float* gi = ws + 50304 + 3200;           // 3H
    float* gh = ws + 50304 + 3200 + 3 * H;   // 3H

    mega_matvec_kernel<<<NB_LOG + NB_GRU, 256, 0, stream>>>(
        word, hidden, w_ih, w_hh, b_ih, b_hh, lin_w, lin_b,
        gi, gh, logits, pm, ps);
    finish_kernel<<<51, 256, 0, stream>>>(logits, pm, ps, gi, gh, hidden, out);
}

// Round 7
// 91.310 us; speedup vs baseline: 1.1950x; 1.1950x over previous
//
#include <hip/hip_runtime.h>
#include <hip/hip_bf16.h>
#include <math.h>

#define H 2048
#define V 50257
#define KV4 (H / 4)          // 512 float4 per row
#define NB_LOG 3142          // ceil(V/16) logits blocks, 16 rows each
#define NB_GRU 768           // 12288 GRU rows / 16
#define NPART NB_LOG

typedef float f4 __attribute__((ext_vector_type(4)));

__device__ __forceinline__ f4 ntload(const f4* p) {
    return __builtin_nontemporal_load(p);
}

__device__ __forceinline__ float wave_reduce_sum(float x) {
    #pragma unroll
    for (int off = 32; off; off >>= 1) x += __shfl_down(x, off, 64);
    return x;
}

// ---------------------------------------------------------------------------
// K_A: mega matvec, one launch for ALL heavy HBM traffic (512 MB).
// EMPIRICAL OPTIMUM (R3 = 91.1 us; 128thr blocks = 97.3; 8 rows/wave = 109.1):
// 256-thread blocks, 4 waves, 4 rows per wave, vector preloaded to registers,
// hot loop = pure weight streaming with 16 loads in flight per lane.
// Blocks [0, NB_LOG): logits rows + block-local softmax partial (m, sumexp).
// Blocks [NB_LOG, ..): GRU rows -> gi / gh.
// ---------------------------------------------------------------------------
__global__ __launch_bounds__(256, 4) void mega_matvec_kernel(
    const float* __restrict__ word, const float* __restrict__ h0,
    const float* __restrict__ w_ih, const float* __restrict__ w_hh,
    const float* __restrict__ b_ih, const float* __restrict__ b_hh,
    const float* __restrict__ lin_w, const float* __restrict__ lin_b,
    float* __restrict__ gi, float* __restrict__ gh,
    float* __restrict__ logits, float* __restrict__ pm,
    float* __restrict__ ps) {
    const int lane = threadIdx.x & 63;
    const int wid = threadIdx.x >> 6;
    __shared__ float lbuf[16];

    const float* Wm;
    const f4* vec;
    const float* bias;
    float* dst;
    int r0, maxrow;
    const bool is_log = ((int)blockIdx.x < NB_LOG);
    if (is_log) {
        Wm = lin_w; vec = reinterpret_cast<const f4*>(h0);
        bias = lin_b; dst = logits;
        r0 = blockIdx.x * 16 + wid * 4;
        maxrow = V;
    } else {
        const int g = blockIdx.x - NB_LOG;         // 0..767
        if (g < 384) {
            Wm = w_ih; vec = reinterpret_cast<const f4*>(word);
            bias = b_ih; dst = gi;
            r0 = g * 16 + wid * 4;
        } else {
            Wm = w_hh; vec = reinterpret_cast<const f4*>(h0);
            bias = b_hh; dst = gh;
            r0 = (g - 384) * 16 + wid * 4;
        }
        maxrow = 3 * H;
    }

    // preload the multiplying vector: lane l uses exactly vec[l + i*64]
    f4 x[8];
    #pragma unroll
    for (int i = 0; i < 8; ++i) x[i] = vec[lane + i * 64];

    const int q0 = min(r0 + 0, maxrow - 1);
    const int q1 = min(r0 + 1, maxrow - 1);
    const int q2 = min(r0 + 2, maxrow - 1);
    const int q3 = min(r0 + 3, maxrow - 1);
    const f4* w0 = reinterpret_cast<const f4*>(Wm + (size_t)q0 * H);
    const f4* w1 = reinterpret_cast<const f4*>(Wm + (size_t)q1 * H);
    const f4* w2 = reinterpret_cast<const f4*>(Wm + (size_t)q2 * H);
    const f4* w3 = reinterpret_cast<const f4*>(Wm + (size_t)q3 * H);

    float a0 = 0.f, a1 = 0.f, a2 = 0.f, a3 = 0.f;
    #pragma unroll 4
    for (int i = 0; i < 8; ++i) {
        const int k = lane + i * 64;
        f4 p0 = ntload(&w0[k]);
        a0 += p0.x * x[i].x + p0.y * x[i].y + p0.z * x[i].z + p0.w * x[i].w;
        f4 p1 = ntload(&w1[k]);
        a1 += p1.x * x[i].x + p1.y * x[i].y + p1.z * x[i].z + p1.w * x[i].w;
        f4 p2 = ntload(&w2[k]);
        a2 += p2.x * x[i].x + p2.y * x[i].y + p2.z * x[i].z + p2.w * x[i].w;
        f4 p3 = ntload(&w3[k]);
        a3 += p3.x * x[i].x + p3.y * x[i].y + p3.z * x[i].z + p3.w * x[i].w;
    }
    a0 = wave_reduce_sum(a0);
    a1 = wave_reduce_sum(a1);
    a2 = wave_reduce_sum(a2);
    a3 = wave_reduce_sum(a3);

    if (lane == 0) {
        const float v0 = a0 + bias[q0];
        const float v1 = a1 + bias[q1];
        const float v2 = a2 + bias[q2];
        const float v3 = a3 + bias[q3];
        if (r0 + 0 < maxrow) dst[r0 + 0] = v0;
        if (r0 + 1 < maxrow) dst[r0 + 1] = v1;
        if (r0 + 2 < maxrow) dst[r0 + 2] = v2;
        if (r0 + 3 < maxrow) dst[r0 + 3] = v3;
        if (is_log) {
            lbuf[wid * 4 + 0] = (r0 + 0 < maxrow) ? v0 : -INFINITY;
            lbuf[wid * 4 + 1] = (r0 + 1 < maxrow) ? v1 : -INFINITY;
            lbuf[wid * 4 + 2] = (r0 + 2 < maxrow) ? v2 : -INFINITY;
            lbuf[wid * 4 + 3] = (r0 + 3 < maxrow) ? v3 : -INFINITY;
        }
    }
    if (is_log) {
        __syncthreads();
        if (threadIdx.x < 16) {
            const float xv = lbuf[threadIdx.x];
            float m = xv;
            #pragma unroll
            for (int off = 8; off; off >>= 1)
                m = fmaxf(m, __shfl_xor(m, off, 16));
            float s = expf(xv - m);         // exp(-inf - m) == 0 for pad rows
            #pragma unroll
            for (int off = 8; off; off >>= 1)
                s += __shfl_xor(s, off, 16);
            if (threadIdx.x == 0) {
                pm[blockIdx.x] = m;
                ps[blockIdx.x] = s;
            }
        }
    }
}

// ---------------------------------------------------------------------------
// K_B: finish. Blocks [0,50): combine NPART partials (L2/L3-resident,
// redundant per block) then probs over 1024 logits each. Block 50: gates.
// ---------------------------------------------------------------------------
__global__ __launch_bounds__(256) void finish_kernel(
    const float* __restrict__ logits, const float* __restrict__ pm,
    const float* __restrict__ ps, const float* __restrict__ gi,
    const float* __restrict__ gh, const float* __restrict__ h0,
    float* __restrict__ out) {
    if ((int)blockIdx.x < 50) {
        __shared__ float redM[4], redS[4];
        __shared__ float sM, sInvS;
        const int lane = threadIdx.x & 63;
        const int wid = threadIdx.x >> 6;

        float M = -INFINITY, S = 0.f;
        for (int p = threadIdx.x; p < NPART; p += 256) {
            const float m = pm[p], s = ps[p];
            const float Mn = fmaxf(M, m);
            S = S * expf(M - Mn) + s * expf(m - Mn);
            M = Mn;
        }
        #pragma unroll
        for (int off = 32; off; off >>= 1) {
            const float Mo = __shfl_xor(M, off, 64);
            const float So = __shfl_xor(S, off, 64);
            const float Mn = fmaxf(M, Mo);
            S = S * expf(M - Mn) + So * expf(Mo - Mn);
            M = Mn;
        }
        if (lane == 0) { redM[wid] = M; redS[wid] = S; }
        __syncthreads();
        if (threadIdx.x == 0) {
            float M4 = redM[0], S4 = redS[0];
            #pragma unroll
            for (int w = 1; w < 4; ++w) {
                const float Mn = fmaxf(M4, redM[w]);
                S4 = S4 * expf(M4 - Mn) + redS[w] * expf(redM[w] - Mn);
                M4 = Mn;
            }
            sM = M4;
            sInvS = 1.f / S4;
        }
        __syncthreads();
        const float gm = sM, gis = sInvS;
        const int base = blockIdx.x * 1024 + threadIdx.x;
        #pragma unroll
        for (int i = 0; i < 4; ++i) {
            const int v = base + i * 256;
            if (v < V) out[v] = expf(logits[v] - gm) * gis;
        }
    } else {
        // gate math: 2048 elements, 256 threads x 8
        #pragma unroll
        for (int i = 0; i < 8; ++i) {
            const int j = threadIdx.x + i * 256;
            const float r = 1.f / (1.f + expf(-(gi[j] + gh[j])));
            const float z = 1.f / (1.f + expf(-(gi[H + j] + gh[H + j])));
            const float n = tanhf(gi[2 * H + j] + r * gh[2 * H + j]);
            out[V + j] = (1.f - z) * n + z * h0[j];
        }
    }
}

extern "C" void kernel_launch(void* const* d_in, const int* in_sizes, int n_in,
                              void* d_out, int out_size, void* d_ws, size_t ws_size,
                              hipStream_t stream) {
    const float* word = (const float*)d_in[0];
    const float* hidden = (const float*)d_in[1];   // h0, 2048 f32
    const float* w_ih = (const float*)d_in[2];
    const float* w_hh = (const float*)d_in[3];
    const float* b_ih = (const float*)d_in[4];
    const float* b_hh = (const float*)d_in[5];
    const float* lin_w = (const float*)d_in[6];
    const float* lin_b = (const float*)d_in[7];

    float* out = (float*)d_out;            // [0:V] probs, [V:V+H] h_new
    float* ws = (float*)d_ws;
    float* logits = ws;                    // V (pad to 50304)
    float* pm = ws + 50304;                // NPART
    float* ps = ws + 50304 + 3200;         // NPART
    float* gi = ws + 50304 + 6400;         // 3H
    float* gh = ws + 50304 + 6400 + 3 * H; // 3H

    mega_matvec_kernel<<<NB_LOG + NB_GRU, 256, 0, stream>>>(
        word, hidden, w_ih, w_hh, b_ih, b_hh, lin_w, lin_b,
        gi, gh, logits, pm, ps);
    finish_kernel<<<51, 256, 0, stream>>>(logits, pm, ps, gi, gh, hidden, out);
}